// Round 3
// baseline (2708.797 us; speedup 1.0000x reference)
//
#include <hip/hip_runtime.h>

using f4 = float4;

constexpr int IN_DIM = 512;
constexpr int DC     = 64;
constexpr int LCB    = 512;
constexpr int CHUNK  = 16384;   // rows per pipeline pass (4 passes over 65536)

__device__ __forceinline__ float wave_sum64(float v) {
#pragma unroll
    for (int m = 1; m < 64; m <<= 1) v += __shfl_xor(v, m, 64);
    return v;
}

// ---------------- codebook L2-normalize (also builds transposed copy) -------
__global__ void cbnorm_kernel(const float* __restrict__ cb, float* __restrict__ cbn,
                              float* __restrict__ cbnT, float* __restrict__ accv) {
    int row  = blockIdx.x * 4 + (threadIdx.x >> 6);  // 0..1535 (k*512 + l)
    int lane = threadIdx.x & 63;
    float v  = cb[(size_t)row * DC + lane];
    float ss = wave_sum64(v * v);
    float n  = sqrtf(ss);
    float o  = v / fmaxf(n, 1e-12f);
    cbn[(size_t)row * DC + lane] = o;
    int k = row >> 9, l = row & 511;
    cbnT[((size_t)k * DC + lane) * LCB + l] = o;
    if (blockIdx.x == 0 && threadIdx.x < 16) accv[threadIdx.x] = 0.f;
}

// ---------------- generic fp32 GEMM: C = act(A @ W + bias), A scaled --------
// A: MxKin row-major, W: KinxN row-major, tile 128x128x32, 8x8 per thread.
template <int RELU>
__global__ __launch_bounds__(256, 4)
void gemm_kernel(const float* __restrict__ A, const float* __restrict__ W,
                 const float* __restrict__ bias, float* __restrict__ C,
                 int Kin, int N, float ascale) {
    constexpr int BM = 128, BN = 128, BK = 32;
    __shared__ alignas(16) float As[BK][BM + 4];  // transposed A tile
    __shared__ alignas(16) float Ws[BK][BN + 4];
    const int tid = threadIdx.x;
    const int tx = tid & 15, ty = tid >> 4;
    const int row0 = blockIdx.x * BM, col0 = blockIdx.y * BN;

    float acc[8][8];
#pragma unroll
    for (int i = 0; i < 8; i++)
#pragma unroll
        for (int j = 0; j < 8; j++) acc[i][j] = 0.f;

    const int aRow = tid >> 3;         // 0..31
    const int aCol = (tid & 7) * 4;    // 0..28
    const int wRow = tid >> 5;         // 0..7
    const int wCol = (tid & 31) * 4;   // 0..124

    for (int kk = 0; kk < Kin; kk += BK) {
#pragma unroll
        for (int it = 0; it < 4; it++) {
            f4 v = *(const f4*)&A[(size_t)(row0 + aRow + it * 32) * Kin + kk + aCol];
            As[aCol + 0][aRow + it * 32] = v.x * ascale;
            As[aCol + 1][aRow + it * 32] = v.y * ascale;
            As[aCol + 2][aRow + it * 32] = v.z * ascale;
            As[aCol + 3][aRow + it * 32] = v.w * ascale;
        }
#pragma unroll
        for (int it = 0; it < 4; it++) {
            f4 v = *(const f4*)&W[(size_t)(kk + wRow + it * 8) * N + col0 + wCol];
            *(f4*)&Ws[wRow + it * 8][wCol] = v;
        }
        __syncthreads();
#pragma unroll
        for (int p = 0; p < BK; p++) {
            f4 a0 = *(const f4*)&As[p][ty * 8];
            f4 a1 = *(const f4*)&As[p][ty * 8 + 4];
            f4 w0 = *(const f4*)&Ws[p][tx * 8];
            f4 w1 = *(const f4*)&Ws[p][tx * 8 + 4];
            float av[8] = {a0.x, a0.y, a0.z, a0.w, a1.x, a1.y, a1.z, a1.w};
            float wv[8] = {w0.x, w0.y, w0.z, w0.w, w1.x, w1.y, w1.z, w1.w};
#pragma unroll
            for (int i = 0; i < 8; i++)
#pragma unroll
                for (int j = 0; j < 8; j++)
                    acc[i][j] = fmaf(av[i], wv[j], acc[i][j]);
        }
        __syncthreads();
    }

#pragma unroll
    for (int i = 0; i < 8; i++) {
        const size_t r = (size_t)row0 + ty * 8 + i;
        float vrow[8];
#pragma unroll
        for (int j = 0; j < 8; j++) {
            float v = acc[i][j] + bias[col0 + tx * 8 + j];
            if (RELU) v = fmaxf(v, 0.f);
            vrow[j] = v;
        }
        *(f4*)&C[r * N + col0 + tx * 8]     = *(f4*)&vrow[0];
        *(f4*)&C[r * N + col0 + tx * 8 + 4] = *(f4*)&vrow[4];
    }
}

// ---------------- GEMM3 + LayerNorm epilogue: enc = LN(A@W3 + b3) -----------
__global__ __launch_bounds__(256, 4)
void gemm_ln_kernel(const float* __restrict__ A, const float* __restrict__ W,
                    const float* __restrict__ bias, const float* __restrict__ gamma,
                    const float* __restrict__ beta, float* __restrict__ enc, int Kin) {
    constexpr int BM = 128, BK = 32;
    __shared__ alignas(16) float As[BK][BM + 4];
    __shared__ alignas(16) float Ws[BK][DC + 4];
    const int tid = threadIdx.x;
    const int tx = tid & 7, ty = tid >> 3;
    const int row0 = blockIdx.x * BM;

    float acc[4][8];
#pragma unroll
    for (int i = 0; i < 4; i++)
#pragma unroll
        for (int j = 0; j < 8; j++) acc[i][j] = 0.f;

    const int aRow = tid >> 3;
    const int aCol = (tid & 7) * 4;
    const int wRow = tid >> 4;
    const int wCol = (tid & 15) * 4;

    for (int kk = 0; kk < Kin; kk += BK) {
#pragma unroll
        for (int it = 0; it < 4; it++) {
            f4 v = *(const f4*)&A[(size_t)(row0 + aRow + it * 32) * Kin + kk + aCol];
            As[aCol + 0][aRow + it * 32] = v.x;
            As[aCol + 1][aRow + it * 32] = v.y;
            As[aCol + 2][aRow + it * 32] = v.z;
            As[aCol + 3][aRow + it * 32] = v.w;
        }
#pragma unroll
        for (int it = 0; it < 2; it++) {
            f4 v = *(const f4*)&W[(size_t)(kk + wRow + it * 16) * DC + wCol];
            *(f4*)&Ws[wRow + it * 16][wCol] = v;
        }
        __syncthreads();
#pragma unroll
        for (int p = 0; p < BK; p++) {
            f4 a  = *(const f4*)&As[p][ty * 4];
            f4 w0 = *(const f4*)&Ws[p][tx * 8];
            f4 w1 = *(const f4*)&Ws[p][tx * 8 + 4];
            float av[4] = {a.x, a.y, a.z, a.w};
            float wv[8] = {w0.x, w0.y, w0.z, w0.w, w1.x, w1.y, w1.z, w1.w};
#pragma unroll
            for (int i = 0; i < 4; i++)
#pragma unroll
                for (int j = 0; j < 8; j++)
                    acc[i][j] = fmaf(av[i], wv[j], acc[i][j]);
        }
        __syncthreads();
    }

#pragma unroll
    for (int i = 0; i < 4; i++) {
        float vrow[8];
#pragma unroll
        for (int j = 0; j < 8; j++) vrow[j] = acc[i][j] + bias[tx * 8 + j];
        float s = 0.f;
#pragma unroll
        for (int j = 0; j < 8; j++) s += vrow[j];
#pragma unroll
        for (int m = 1; m < 8; m <<= 1) s += __shfl_xor(s, m, 8);
        float mu = s * (1.f / 64.f);
        float d2 = 0.f;
#pragma unroll
        for (int j = 0; j < 8; j++) { float d = vrow[j] - mu; d2 = fmaf(d, d, d2); }
#pragma unroll
        for (int m = 1; m < 8; m <<= 1) d2 += __shfl_xor(d2, m, 8);
        float rs = 1.f / sqrtf(d2 * (1.f / 64.f) + 1e-5f);
#pragma unroll
        for (int j = 0; j < 8; j++) {
            int c = tx * 8 + j;
            vrow[j] = (vrow[j] - mu) * rs * gamma[c] + beta[c];
        }
        const size_t r = (size_t)row0 + ty * 4 + i;
        *(f4*)&enc[r * DC + tx * 8]     = *(f4*)&vrow[0];
        *(f4*)&enc[r * DC + tx * 8 + 4] = *(f4*)&vrow[4];
    }
}

// ---------------- quantize scores (f64 accumulate) -> argmax index ----------
// 128 rows/block; 512 codebook entries in 8 chunks of 64. Unnormalized enc
// (positive row scale drops out of argmax); f64 acc minimizes tie flips.
__global__ __launch_bounds__(256, 2)
void quant_idx_kernel(const float* __restrict__ enc, const float* __restrict__ cbT,
                      int* __restrict__ idx_buf) {
    constexpr int BM = 128;
    __shared__ alignas(16) float Es[DC][BM + 4];   // enc tile, transposed [d][r]
    __shared__ alignas(16) float Cs[DC][64 + 4];   // cbT chunk [d][l']
    const int tid = threadIdx.x;
    const int tx = tid & 7, ty = tid >> 3;         // ty 0..31 (4 rows), tx 0..7
    const int row0 = blockIdx.x * BM;

    {   // load enc tile transposed
        const int r  = tid >> 1;
        const int c0 = (tid & 1) * 32;
#pragma unroll
        for (int i = 0; i < 8; i++) {
            f4 v = *(const f4*)&enc[(size_t)(row0 + r) * DC + c0 + i * 4];
            Es[c0 + i * 4 + 0][r] = v.x;
            Es[c0 + i * 4 + 1][r] = v.y;
            Es[c0 + i * 4 + 2][r] = v.z;
            Es[c0 + i * 4 + 3][r] = v.w;
        }
    }

    double mx[4]; int mi[4];
#pragma unroll
    for (int i = 0; i < 4; i++) { mx[i] = -1.0e300; mi[i] = 0; }

    for (int lc = 0; lc < LCB; lc += 64) {
        __syncthreads();
        {
            const int p  = tid >> 2;
            const int c0 = (tid & 3) * 16;
#pragma unroll
            for (int i = 0; i < 4; i++)
                *(f4*)&Cs[p][c0 + i * 4] =
                    *(const f4*)&cbT[(size_t)p * LCB + lc + c0 + i * 4];
        }
        __syncthreads();
        double sc[4][8];
#pragma unroll
        for (int i = 0; i < 4; i++)
#pragma unroll
            for (int j = 0; j < 8; j++) sc[i][j] = 0.0;
#pragma unroll
        for (int p = 0; p < DC; p++) {
            f4 a  = *(const f4*)&Es[p][ty * 4];
            f4 w0 = *(const f4*)&Cs[p][tx * 8];
            f4 w1 = *(const f4*)&Cs[p][tx * 8 + 4];
            double av[4] = {a.x, a.y, a.z, a.w};
            double wv[8] = {w0.x, w0.y, w0.z, w0.w, w1.x, w1.y, w1.z, w1.w};
#pragma unroll
            for (int i = 0; i < 4; i++)
#pragma unroll
                for (int j = 0; j < 8; j++)
                    sc[i][j] = fma(av[i], wv[j], sc[i][j]);
        }
#pragma unroll
        for (int i = 0; i < 4; i++)
#pragma unroll
            for (int j = 0; j < 8; j++) {
                int l = lc + tx * 8 + j;
                if (sc[i][j] > mx[i]) { mx[i] = sc[i][j]; mi[i] = l; }
            }
    }

    // argmax reduce over the 8 tx lanes (first-max tie rule: smaller index wins)
#pragma unroll
    for (int m = 1; m < 8; m <<= 1)
#pragma unroll
        for (int i = 0; i < 4; i++) {
            double omx = __shfl_xor(mx[i], m, 8);
            int    omi = __shfl_xor(mi[i], m, 8);
            if (omx > mx[i] || (omx == mx[i] && omi < mi[i])) { mx[i] = omx; mi[i] = omi; }
        }

    if (tx == 0) {
#pragma unroll
        for (int i = 0; i < 4; i++)
            idx_buf[row0 + ty * 4 + i] = mi[i];
    }
}

// ---------------- gather: qs = sum_k cbn[idx_k], sse, tokens ----------------
__global__ __launch_bounds__(256, 8)
void gather_kernel(const float* __restrict__ enc3, const float* __restrict__ cbn,
                   const int* __restrict__ idx3, float* __restrict__ qs,
                   float* __restrict__ out_tok, float* __restrict__ sse_acc,
                   int chunk_rows, int row_off_glob) {
    __shared__ float red[4];
    const int tid  = threadIdx.x;
    const int lane = tid & 63;
    const int r    = blockIdx.x * 4 + (tid >> 6);   // row within chunk
    float qsum = 0.f, ds = 0.f;
#pragma unroll
    for (int k = 0; k < 3; k++) {
        int idxk = idx3[k * chunk_rows + r];
        float e  = enc3[((size_t)k * chunk_rows + r) * DC + lane];
        float q  = cbn[((size_t)(k * LCB + idxk)) * DC + lane];
        qsum += q;
        float d = e - q;
        ds = fmaf(d, d, ds);
        if (lane == 0)
            out_tok[(size_t)(row_off_glob + r) * 3 + k] = (float)idxk;
    }
    qs[(size_t)r * DC + lane] = qsum;
    ds = wave_sum64(ds);
    if (lane == 0) red[tid >> 6] = ds;
    __syncthreads();
    if (tid == 0) atomicAdd(sse_acc, red[0] + red[1] + red[2] + red[3]);
}

// ---------------- decoder final GEMM + f32 store + recon SSE ----------------
__global__ __launch_bounds__(256, 4)
void gemm_dec_out_kernel(const float* __restrict__ A, const float* __restrict__ W,
                         const float* __restrict__ bias, const float* __restrict__ x,
                         float* __restrict__ rec, float* __restrict__ sse_acc,
                         int Kin, int N) {
    constexpr int BM = 128, BN = 128, BK = 32;
    __shared__ alignas(16) float As[BK][BM + 4];
    __shared__ alignas(16) float Ws[BK][BN + 4];
    __shared__ float red[4];
    const int tid = threadIdx.x;
    const int tx = tid & 15, ty = tid >> 4;
    const int row0 = blockIdx.x * BM, col0 = blockIdx.y * BN;

    float acc[8][8];
#pragma unroll
    for (int i = 0; i < 8; i++)
#pragma unroll
        for (int j = 0; j < 8; j++) acc[i][j] = 0.f;

    const int aRow = tid >> 3;
    const int aCol = (tid & 7) * 4;
    const int wRow = tid >> 5;
    const int wCol = (tid & 31) * 4;

    for (int kk = 0; kk < Kin; kk += BK) {
#pragma unroll
        for (int it = 0; it < 4; it++) {
            f4 v = *(const f4*)&A[(size_t)(row0 + aRow + it * 32) * Kin + kk + aCol];
            As[aCol + 0][aRow + it * 32] = v.x;
            As[aCol + 1][aRow + it * 32] = v.y;
            As[aCol + 2][aRow + it * 32] = v.z;
            As[aCol + 3][aRow + it * 32] = v.w;
        }
#pragma unroll
        for (int it = 0; it < 4; it++) {
            f4 v = *(const f4*)&W[(size_t)(kk + wRow + it * 8) * N + col0 + wCol];
            *(f4*)&Ws[wRow + it * 8][wCol] = v;
        }
        __syncthreads();
#pragma unroll
        for (int p = 0; p < BK; p++) {
            f4 a0 = *(const f4*)&As[p][ty * 8];
            f4 a1 = *(const f4*)&As[p][ty * 8 + 4];
            f4 w0 = *(const f4*)&Ws[p][tx * 8];
            f4 w1 = *(const f4*)&Ws[p][tx * 8 + 4];
            float av[8] = {a0.x, a0.y, a0.z, a0.w, a1.x, a1.y, a1.z, a1.w};
            float wv[8] = {w0.x, w0.y, w0.z, w0.w, w1.x, w1.y, w1.z, w1.w};
#pragma unroll
            for (int i = 0; i < 8; i++)
#pragma unroll
                for (int j = 0; j < 8; j++)
                    acc[i][j] = fmaf(av[i], wv[j], acc[i][j]);
        }
        __syncthreads();
    }

    float sse = 0.f;
#pragma unroll
    for (int i = 0; i < 8; i++) {
        const size_t r = (size_t)row0 + ty * 8 + i;
        f4 x0 = *(const f4*)&x[r * N + col0 + tx * 8];
        f4 x1 = *(const f4*)&x[r * N + col0 + tx * 8 + 4];
        float xv[8] = {x0.x, x0.y, x0.z, x0.w, x1.x, x1.y, x1.z, x1.w};
        float vrow[8];
#pragma unroll
        for (int j = 0; j < 8; j++) {
            float v = acc[i][j] + bias[col0 + tx * 8 + j];
            float d = v - xv[j];
            sse = fmaf(d, d, sse);
            vrow[j] = v;
        }
        *(f4*)&rec[r * N + col0 + tx * 8]     = *(f4*)&vrow[0];
        *(f4*)&rec[r * N + col0 + tx * 8 + 4] = *(f4*)&vrow[4];
    }
    sse = wave_sum64(sse);
    if ((tid & 63) == 0) red[tid >> 6] = sse;
    __syncthreads();
    if (tid == 0) atomicAdd(sse_acc, red[0] + red[1] + red[2] + red[3]);
}

// ---------------- finalize scalars ----------------
__global__ void finalize_kernel(const float* __restrict__ accv,
                                float* __restrict__ outs,
                                float inv_rec, float inv_cb) {
    if (threadIdx.x == 0) {
        outs[0] = accv[1] * inv_rec;     // recon_loss
        float cbl = accv[0] * inv_cb;
        outs[1] = cbl;                   // codebook_loss
        outs[2] = cbl;                   // commitment_loss (forward-equal)
    }
}

extern "C" void kernel_launch(void* const* d_in, const int* in_sizes, int n_in,
                              void* d_out, int out_size, void* d_ws, size_t ws_size,
                              hipStream_t stream) {
    const float* x     = (const float*)d_in[0];
    const float* W1    = (const float*)d_in[1];
    const float* b1    = (const float*)d_in[2];
    const float* W2    = (const float*)d_in[3];
    const float* b2    = (const float*)d_in[4];
    const float* W3    = (const float*)d_in[5];
    const float* b3    = (const float*)d_in[6];
    const float* gamma = (const float*)d_in[7];
    const float* beta  = (const float*)d_in[8];
    const float* cb    = (const float*)d_in[9];
    const float* D1    = (const float*)d_in[10];
    const float* c1    = (const float*)d_in[11];
    const float* D2    = (const float*)d_in[12];
    const float* c2    = (const float*)d_in[13];
    const float* D3    = (const float*)d_in[14];
    const float* c3    = (const float*)d_in[15];
    const int M = in_sizes[0] / IN_DIM;   // 65536

    float* out     = (float*)d_out;       // float32 output buffer (see round-2 analysis)
    float* out_tok = out;                          // M*3
    float* out_rec = out + (size_t)M * 3;          // M*512
    float* out_sc  = out_rec + (size_t)M * IN_DIM; // 3 scalars

    // ws layout (~42.5 MB)
    float* ws    = (float*)d_ws;
    float* accv  = ws;                                   // 16
    float* cbn   = accv + 16;                            // 3*512*64
    float* cbnT  = cbn + 3 * 512 * 64;                   // 3*64*512
    int*   idx3  = (int*)(cbnT + 3 * 512 * 64);          // 3*CHUNK
    float* qs    = (float*)(idx3 + 3 * CHUNK);           // CHUNK*64
    float* enc3  = qs + (size_t)CHUNK * 64;              // 3*CHUNK*64
    float* H2    = enc3 + (size_t)3 * CHUNK * 64;        // CHUNK*128
    float* H1    = H2 + (size_t)CHUNK * 128;             // CHUNK*256

    cbnorm_kernel<<<dim3(3 * 512 / 4), dim3(256), 0, stream>>>(cb, cbn, cbnT, accv);

    for (int off = 0; off < M; off += CHUNK) {
        const float* xc  = x + (size_t)off * IN_DIM;
        float*       rcc = out_rec + (size_t)off * IN_DIM;

        for (int k = 0; k < 3; k++) {
            float* enck = enc3 + (size_t)k * CHUNK * DC;
            gemm_kernel<1><<<dim3(CHUNK / 128, 2), dim3(256), 0, stream>>>(
                xc, W1 + (size_t)k * 512 * 256, b1 + k * 256, H1, 512, 256, 1.f);
            gemm_kernel<1><<<dim3(CHUNK / 128, 1), dim3(256), 0, stream>>>(
                H1, W2 + (size_t)k * 256 * 128, b2 + k * 128, H2, 256, 128, 1.f);
            gemm_ln_kernel<<<dim3(CHUNK / 128), dim3(256), 0, stream>>>(
                H2, W3 + (size_t)k * 128 * 64, b3 + k * 64, gamma, beta, enck, 128);
            quant_idx_kernel<<<dim3(CHUNK / 128), dim3(256), 0, stream>>>(
                enck, cbnT + (size_t)k * 64 * 512, idx3 + k * CHUNK);
        }
        gather_kernel<<<dim3(CHUNK / 4), dim3(256), 0, stream>>>(
            enc3, cbn, idx3, qs, out_tok, accv + 0, CHUNK, off);

        // decoder: avg_q = qs/3 folded into A-load scale
        gemm_kernel<1><<<dim3(CHUNK / 128, 1), dim3(256), 0, stream>>>(
            qs, D1, c1, H2, 64, 128, 1.f / 3.f);
        gemm_kernel<1><<<dim3(CHUNK / 128, 2), dim3(256), 0, stream>>>(
            H2, D2, c2, H1, 128, 256, 1.f);
        gemm_dec_out_kernel<<<dim3(CHUNK / 128, 4), dim3(256), 0, stream>>>(
            H1, D3, c3, xc, rcc, accv + 1, 256, 512);
    }

    finalize_kernel<<<dim3(1), dim3(64), 0, stream>>>(
        accv, out_sc, 1.f / ((float)M * IN_DIM), 1.f / ((float)M * DC));
}

// Round 4
// 1374.209 us; speedup vs baseline: 1.9712x; 1.9712x over previous
//
#include <hip/hip_runtime.h>

using f4 = float4;

constexpr int IN_DIM = 512;
constexpr int DC     = 64;
constexpr int LCB    = 512;

__device__ __forceinline__ float wave_sum64(float v) {
#pragma unroll
    for (int m = 1; m < 64; m <<= 1) v += __shfl_xor(v, m, 64);
    return v;
}

// ---------------- codebook L2-normalize (also builds transposed copy) -------
__global__ void cbnorm_kernel(const float* __restrict__ cb, float* __restrict__ cbn,
                              float* __restrict__ cbnT, float* __restrict__ accv) {
    int row  = blockIdx.x * 4 + (threadIdx.x >> 6);  // 0..1535 (k*512 + l)
    int lane = threadIdx.x & 63;
    float v  = cb[(size_t)row * DC + lane];
    float ss = wave_sum64(v * v);
    float n  = sqrtf(ss);
    float o  = v / fmaxf(n, 1e-12f);
    cbn[(size_t)row * DC + lane] = o;
    int k = row >> 9, l = row & 511;
    cbnT[((size_t)k * DC + lane) * LCB + l] = o;
    if (blockIdx.x == 0 && threadIdx.x < 16) accv[threadIdx.x] = 0.f;
}

// ---------------- generic fp32 GEMM: C = act(A @ W + bias) ------------------
// A: MxKin row-major, W: KinxN row-major, tile 128x128x32, 8x8 per thread.
// blockIdx.z selects plane k via strides aK/wK/bK/cK. SUM3: A-load sums 3
// planes spaced sumStride apart (for avg_q) before scaling.
template <int RELU, int SUM3>
__global__ __launch_bounds__(256, 4)
void gemm_kernel(const float* __restrict__ A, const float* __restrict__ W,
                 const float* __restrict__ bias, float* __restrict__ C,
                 int Kin, int N, float ascale,
                 size_t aK, size_t wK, size_t bK, size_t cK, size_t sumStride) {
    constexpr int BM = 128, BK = 32;
    __shared__ alignas(16) float As[BK][BM + 4];  // transposed A tile
    __shared__ alignas(16) float Ws[BK][128 + 4];
    const int z = blockIdx.z;
    A += (size_t)z * aK;  W += (size_t)z * wK;
    bias += (size_t)z * bK;  C += (size_t)z * cK;
    const int tid = threadIdx.x;
    const int tx = tid & 15, ty = tid >> 4;
    const int row0 = blockIdx.x * BM, col0 = blockIdx.y * 128;

    float acc[8][8];
#pragma unroll
    for (int i = 0; i < 8; i++)
#pragma unroll
        for (int j = 0; j < 8; j++) acc[i][j] = 0.f;

    const int aRow = tid >> 3;         // 0..31
    const int aCol = (tid & 7) * 4;    // 0..28
    const int wRow = tid >> 5;         // 0..7
    const int wCol = (tid & 31) * 4;   // 0..124

    for (int kk = 0; kk < Kin; kk += BK) {
#pragma unroll
        for (int it = 0; it < 4; it++) {
            const size_t aoff = (size_t)(row0 + aRow + it * 32) * Kin + kk + aCol;
            f4 v = *(const f4*)&A[aoff];
            if (SUM3) {
                f4 v2 = *(const f4*)&A[aoff + sumStride];
                f4 v3 = *(const f4*)&A[aoff + 2 * sumStride];
                v.x += v2.x + v3.x; v.y += v2.y + v3.y;
                v.z += v2.z + v3.z; v.w += v2.w + v3.w;
            }
            As[aCol + 0][aRow + it * 32] = v.x * ascale;
            As[aCol + 1][aRow + it * 32] = v.y * ascale;
            As[aCol + 2][aRow + it * 32] = v.z * ascale;
            As[aCol + 3][aRow + it * 32] = v.w * ascale;
        }
#pragma unroll
        for (int it = 0; it < 4; it++) {
            f4 v = *(const f4*)&W[(size_t)(kk + wRow + it * 8) * N + col0 + wCol];
            *(f4*)&Ws[wRow + it * 8][wCol] = v;
        }
        __syncthreads();
#pragma unroll
        for (int p = 0; p < BK; p++) {
            f4 a0 = *(const f4*)&As[p][ty * 8];
            f4 a1 = *(const f4*)&As[p][ty * 8 + 4];
            f4 w0 = *(const f4*)&Ws[p][tx * 8];
            f4 w1 = *(const f4*)&Ws[p][tx * 8 + 4];
            float av[8] = {a0.x, a0.y, a0.z, a0.w, a1.x, a1.y, a1.z, a1.w};
            float wv[8] = {w0.x, w0.y, w0.z, w0.w, w1.x, w1.y, w1.z, w1.w};
#pragma unroll
            for (int i = 0; i < 8; i++)
#pragma unroll
                for (int j = 0; j < 8; j++)
                    acc[i][j] = fmaf(av[i], wv[j], acc[i][j]);
        }
        __syncthreads();
    }

#pragma unroll
    for (int i = 0; i < 8; i++) {
        const size_t r = (size_t)row0 + ty * 8 + i;
        float vrow[8];
#pragma unroll
        for (int j = 0; j < 8; j++) {
            float v = acc[i][j] + bias[col0 + tx * 8 + j];
            if (RELU) v = fmaxf(v, 0.f);
            vrow[j] = v;
        }
        *(f4*)&C[r * N + col0 + tx * 8]     = *(f4*)&vrow[0];
        *(f4*)&C[r * N + col0 + tx * 8 + 4] = *(f4*)&vrow[4];
    }
}

// ---------------- GEMM3 + LayerNorm epilogue: enc = LN(A@W3 + b3) -----------
// blockIdx.y selects k-plane.
__global__ __launch_bounds__(256, 4)
void gemm_ln_kernel(const float* __restrict__ A, const float* __restrict__ W,
                    const float* __restrict__ bias, const float* __restrict__ gamma,
                    const float* __restrict__ beta, float* __restrict__ enc, int Kin,
                    size_t aK, size_t wK, size_t bK, size_t eK) {
    constexpr int BM = 128, BK = 32;
    __shared__ alignas(16) float As[BK][BM + 4];
    __shared__ alignas(16) float Ws[BK][DC + 4];
    const int z = blockIdx.y;
    A += (size_t)z * aK;  W += (size_t)z * wK;
    bias += (size_t)z * bK;  enc += (size_t)z * eK;
    const int tid = threadIdx.x;
    const int tx = tid & 7, ty = tid >> 3;
    const int row0 = blockIdx.x * BM;

    float acc[4][8];
#pragma unroll
    for (int i = 0; i < 4; i++)
#pragma unroll
        for (int j = 0; j < 8; j++) acc[i][j] = 0.f;

    const int aRow = tid >> 3;
    const int aCol = (tid & 7) * 4;
    const int wRow = tid >> 4;
    const int wCol = (tid & 15) * 4;

    for (int kk = 0; kk < Kin; kk += BK) {
#pragma unroll
        for (int it = 0; it < 4; it++) {
            f4 v = *(const f4*)&A[(size_t)(row0 + aRow + it * 32) * Kin + kk + aCol];
            As[aCol + 0][aRow + it * 32] = v.x;
            As[aCol + 1][aRow + it * 32] = v.y;
            As[aCol + 2][aRow + it * 32] = v.z;
            As[aCol + 3][aRow + it * 32] = v.w;
        }
#pragma unroll
        for (int it = 0; it < 2; it++) {
            f4 v = *(const f4*)&W[(size_t)(kk + wRow + it * 16) * DC + wCol];
            *(f4*)&Ws[wRow + it * 16][wCol] = v;
        }
        __syncthreads();
#pragma unroll
        for (int p = 0; p < BK; p++) {
            f4 a  = *(const f4*)&As[p][ty * 4];
            f4 w0 = *(const f4*)&Ws[p][tx * 8];
            f4 w1 = *(const f4*)&Ws[p][tx * 8 + 4];
            float av[4] = {a.x, a.y, a.z, a.w};
            float wv[8] = {w0.x, w0.y, w0.z, w0.w, w1.x, w1.y, w1.z, w1.w};
#pragma unroll
            for (int i = 0; i < 4; i++)
#pragma unroll
                for (int j = 0; j < 8; j++)
                    acc[i][j] = fmaf(av[i], wv[j], acc[i][j]);
        }
        __syncthreads();
    }

#pragma unroll
    for (int i = 0; i < 4; i++) {
        float vrow[8];
#pragma unroll
        for (int j = 0; j < 8; j++) vrow[j] = acc[i][j] + bias[tx * 8 + j];
        float s = 0.f;
#pragma unroll
        for (int j = 0; j < 8; j++) s += vrow[j];
#pragma unroll
        for (int m = 1; m < 8; m <<= 1) s += __shfl_xor(s, m, 8);
        float mu = s * (1.f / 64.f);
        float d2 = 0.f;
#pragma unroll
        for (int j = 0; j < 8; j++) { float d = vrow[j] - mu; d2 = fmaf(d, d, d2); }
#pragma unroll
        for (int m = 1; m < 8; m <<= 1) d2 += __shfl_xor(d2, m, 8);
        float rs = 1.f / sqrtf(d2 * (1.f / 64.f) + 1e-5f);
#pragma unroll
        for (int j = 0; j < 8; j++) {
            int c = tx * 8 + j;
            vrow[j] = (vrow[j] - mu) * rs * gamma[c] + beta[c];
        }
        const size_t r = (size_t)row0 + ty * 4 + i;
        *(f4*)&enc[r * DC + tx * 8]     = *(f4*)&vrow[0];
        *(f4*)&enc[r * DC + tx * 8 + 4] = *(f4*)&vrow[4];
    }
}

// ---------------- quantize (f64 scores) + tokens + SSE + q in-place ---------
// blockIdx.y selects k. Overwrites enc plane with chosen codeword q.
__global__ __launch_bounds__(256, 2)
void quant_kernel(float* __restrict__ enc, const float* __restrict__ cbT,
                  const float* __restrict__ cbn, float* __restrict__ out_tok,
                  float* __restrict__ sse_acc, int row_off_glob,
                  size_t eK, size_t cbTK, size_t cbnK) {
    constexpr int BM = 128;
    __shared__ alignas(16) float Es[DC][BM + 4];   // enc tile, transposed [d][r]
    __shared__ alignas(16) float Cs[DC][64 + 4];   // cbT chunk [d][l']
    __shared__ float red[4];
    const int k = blockIdx.y;
    enc += (size_t)k * eK;
    cbT += (size_t)k * cbTK;
    cbn += (size_t)k * cbnK;
    const int tid = threadIdx.x;
    const int tx = tid & 7, ty = tid >> 3;         // ty 0..31 (4 rows), tx 0..7
    const int row0 = blockIdx.x * BM;

    {   // load enc tile transposed
        const int r  = tid >> 1;
        const int c0 = (tid & 1) * 32;
#pragma unroll
        for (int i = 0; i < 8; i++) {
            f4 v = *(const f4*)&enc[(size_t)(row0 + r) * DC + c0 + i * 4];
            Es[c0 + i * 4 + 0][r] = v.x;
            Es[c0 + i * 4 + 1][r] = v.y;
            Es[c0 + i * 4 + 2][r] = v.z;
            Es[c0 + i * 4 + 3][r] = v.w;
        }
    }

    double mx[4]; int mi[4];
#pragma unroll
    for (int i = 0; i < 4; i++) { mx[i] = -1.0e300; mi[i] = 0; }

    for (int lc = 0; lc < LCB; lc += 64) {
        __syncthreads();
        {
            const int p  = tid >> 2;
            const int c0 = (tid & 3) * 16;
#pragma unroll
            for (int i = 0; i < 4; i++)
                *(f4*)&Cs[p][c0 + i * 4] =
                    *(const f4*)&cbT[(size_t)p * LCB + lc + c0 + i * 4];
        }
        __syncthreads();
        double sc[4][8];
#pragma unroll
        for (int i = 0; i < 4; i++)
#pragma unroll
            for (int j = 0; j < 8; j++) sc[i][j] = 0.0;
#pragma unroll
        for (int p = 0; p < DC; p++) {
            f4 a  = *(const f4*)&Es[p][ty * 4];
            f4 w0 = *(const f4*)&Cs[p][tx * 8];
            f4 w1 = *(const f4*)&Cs[p][tx * 8 + 4];
            double av[4] = {a.x, a.y, a.z, a.w};
            double wv[8] = {w0.x, w0.y, w0.z, w0.w, w1.x, w1.y, w1.z, w1.w};
#pragma unroll
            for (int i = 0; i < 4; i++)
#pragma unroll
                for (int j = 0; j < 8; j++)
                    sc[i][j] = fma(av[i], wv[j], sc[i][j]);
        }
#pragma unroll
        for (int i = 0; i < 4; i++)
#pragma unroll
            for (int j = 0; j < 8; j++) {
                int l = lc + tx * 8 + j;
                if (sc[i][j] > mx[i]) { mx[i] = sc[i][j]; mi[i] = l; }
            }
    }

    // argmax reduce over the 8 tx lanes (first-max tie rule: smaller index wins)
#pragma unroll
    for (int m = 1; m < 8; m <<= 1)
#pragma unroll
        for (int i = 0; i < 4; i++) {
            double omx = __shfl_xor(mx[i], m, 8);
            int    omi = __shfl_xor(mi[i], m, 8);
            if (omx > mx[i] || (omx == mx[i] && omi < mi[i])) { mx[i] = omx; mi[i] = omi; }
        }

    // epilogue: sse, token write, overwrite enc plane with q
    float sse = 0.f;
#pragma unroll
    for (int i = 0; i < 4; i++) {
        const int rl = ty * 4 + i;
        const size_t r = (size_t)row0 + rl;
        f4 q0 = *(const f4*)&cbn[(size_t)mi[i] * DC + tx * 8];
        f4 q1 = *(const f4*)&cbn[(size_t)mi[i] * DC + tx * 8 + 4];
        float qv[8] = {q0.x, q0.y, q0.z, q0.w, q1.x, q1.y, q1.z, q1.w};
#pragma unroll
        for (int j = 0; j < 8; j++) {
            float e = Es[tx * 8 + j][rl];
            float d = e - qv[j];
            sse = fmaf(d, d, sse);
        }
        *(f4*)&enc[r * DC + tx * 8]     = q0;
        *(f4*)&enc[r * DC + tx * 8 + 4] = q1;
        if (tx == 0) out_tok[(size_t)(row_off_glob + r) * 3 + k] = (float)mi[i];
    }
    sse = wave_sum64(sse);
    if ((tid & 63) == 0) red[tid >> 6] = sse;
    __syncthreads();
    if (tid == 0) atomicAdd(sse_acc, red[0] + red[1] + red[2] + red[3]);
}

// ---------------- decoder final GEMM + f32 store + recon SSE ----------------
__global__ __launch_bounds__(256, 4)
void gemm_dec_out_kernel(const float* __restrict__ A, const float* __restrict__ W,
                         const float* __restrict__ bias, const float* __restrict__ x,
                         float* __restrict__ rec, float* __restrict__ sse_acc,
                         int Kin, int N) {
    constexpr int BM = 128, BN = 128, BK = 32;
    __shared__ alignas(16) float As[BK][BM + 4];
    __shared__ alignas(16) float Ws[BK][BN + 4];
    __shared__ float red[4];
    const int tid = threadIdx.x;
    const int tx = tid & 15, ty = tid >> 4;
    const int row0 = blockIdx.x * BM, col0 = blockIdx.y * BN;

    float acc[8][8];
#pragma unroll
    for (int i = 0; i < 8; i++)
#pragma unroll
        for (int j = 0; j < 8; j++) acc[i][j] = 0.f;

    const int aRow = tid >> 3;
    const int aCol = (tid & 7) * 4;
    const int wRow = tid >> 5;
    const int wCol = (tid & 31) * 4;

    for (int kk = 0; kk < Kin; kk += BK) {
#pragma unroll
        for (int it = 0; it < 4; it++) {
            f4 v = *(const f4*)&A[(size_t)(row0 + aRow + it * 32) * Kin + kk + aCol];
            As[aCol + 0][aRow + it * 32] = v.x;
            As[aCol + 1][aRow + it * 32] = v.y;
            As[aCol + 2][aRow + it * 32] = v.z;
            As[aCol + 3][aRow + it * 32] = v.w;
        }
#pragma unroll
        for (int it = 0; it < 4; it++) {
            f4 v = *(const f4*)&W[(size_t)(kk + wRow + it * 8) * N + col0 + wCol];
            *(f4*)&Ws[wRow + it * 8][wCol] = v;
        }
        __syncthreads();
#pragma unroll
        for (int p = 0; p < BK; p++) {
            f4 a0 = *(const f4*)&As[p][ty * 8];
            f4 a1 = *(const f4*)&As[p][ty * 8 + 4];
            f4 w0 = *(const f4*)&Ws[p][tx * 8];
            f4 w1 = *(const f4*)&Ws[p][tx * 8 + 4];
            float av[8] = {a0.x, a0.y, a0.z, a0.w, a1.x, a1.y, a1.z, a1.w};
            float wv[8] = {w0.x, w0.y, w0.z, w0.w, w1.x, w1.y, w1.z, w1.w};
#pragma unroll
            for (int i = 0; i < 8; i++)
#pragma unroll
                for (int j = 0; j < 8; j++)
                    acc[i][j] = fmaf(av[i], wv[j], acc[i][j]);
        }
        __syncthreads();
    }

    float sse = 0.f;
#pragma unroll
    for (int i = 0; i < 8; i++) {
        const size_t r = (size_t)row0 + ty * 8 + i;
        f4 x0 = *(const f4*)&x[r * N + col0 + tx * 8];
        f4 x1 = *(const f4*)&x[r * N + col0 + tx * 8 + 4];
        float xv[8] = {x0.x, x0.y, x0.z, x0.w, x1.x, x1.y, x1.z, x1.w};
        float vrow[8];
#pragma unroll
        for (int j = 0; j < 8; j++) {
            float v = acc[i][j] + bias[col0 + tx * 8 + j];
            float d = v - xv[j];
            sse = fmaf(d, d, sse);
            vrow[j] = v;
        }
        *(f4*)&rec[r * N + col0 + tx * 8]     = *(f4*)&vrow[0];
        *(f4*)&rec[r * N + col0 + tx * 8 + 4] = *(f4*)&vrow[4];
    }
    sse = wave_sum64(sse);
    if ((tid & 63) == 0) red[tid >> 6] = sse;
    __syncthreads();
    if (tid == 0) atomicAdd(sse_acc, red[0] + red[1] + red[2] + red[3]);
}

// ---------------- finalize scalars ----------------
__global__ void finalize_kernel(const float* __restrict__ accv,
                                float* __restrict__ outs,
                                float inv_rec, float inv_cb) {
    if (threadIdx.x == 0) {
        outs[0] = accv[1] * inv_rec;     // recon_loss
        float cbl = accv[0] * inv_cb;
        outs[1] = cbl;                   // codebook_loss
        outs[2] = cbl;                   // commitment_loss (forward-equal)
    }
}

extern "C" void kernel_launch(void* const* d_in, const int* in_sizes, int n_in,
                              void* d_out, int out_size, void* d_ws, size_t ws_size,
                              hipStream_t stream) {
    const float* x     = (const float*)d_in[0];
    const float* W1    = (const float*)d_in[1];
    const float* b1    = (const float*)d_in[2];
    const float* W2    = (const float*)d_in[3];
    const float* b2    = (const float*)d_in[4];
    const float* W3    = (const float*)d_in[5];
    const float* b3    = (const float*)d_in[6];
    const float* gamma = (const float*)d_in[7];
    const float* beta  = (const float*)d_in[8];
    const float* cb    = (const float*)d_in[9];
    const float* D1    = (const float*)d_in[10];
    const float* c1    = (const float*)d_in[11];
    const float* D2    = (const float*)d_in[12];
    const float* c2    = (const float*)d_in[13];
    const float* D3    = (const float*)d_in[14];
    const float* c3    = (const float*)d_in[15];
    const int M = in_sizes[0] / IN_DIM;   // 65536

    float* out     = (float*)d_out;       // float32 output buffer
    float* out_tok = out;                          // M*3
    float* out_rec = out + (size_t)M * 3;          // M*512
    float* out_sc  = out_rec + (size_t)M * IN_DIM; // 3 scalars

    // pick the largest chunk that fits ws: per-row = qenc3(192) + H1k(768) + H2k(384) floats
    const size_t fixedB  = (size_t)(16 + 2 * 3 * LCB * DC) * 4;
    const size_t perRowB = (size_t)(3 * DC + 3 * 256 + 3 * 128) * 4;   // 5376
    int C = 4096;
    for (int cand = 65536; cand >= 4096; cand >>= 1)
        if (fixedB + (size_t)cand * perRowB <= ws_size) { C = cand; break; }

    float* ws    = (float*)d_ws;
    float* accv  = ws;                                   // 16
    float* cbn   = accv + 16;                            // 3*512*64
    float* cbnT  = cbn + 3 * LCB * DC;                   // 3*64*512
    float* enc3  = cbnT + 3 * DC * LCB;                  // 3*C*64 (enc, then q)
    float* H1    = enc3 + (size_t)3 * C * DC;            // 3*C*256
    float* H2    = H1 + (size_t)3 * C * 256;             // 3*C*128

    cbnorm_kernel<<<dim3(3 * LCB / 4), dim3(256), 0, stream>>>(cb, cbn, cbnT, accv);

    for (int off = 0; off < M; off += C) {
        const float* xc  = x + (size_t)off * IN_DIM;
        float*       rcc = out_rec + (size_t)off * IN_DIM;

        // encoder, k-batched via grid.z
        gemm_kernel<1, 0><<<dim3(C / 128, 2, 3), dim3(256), 0, stream>>>(
            xc, W1, b1, H1, 512, 256, 1.f,
            0, (size_t)512 * 256, 256, (size_t)C * 256, 0);
        gemm_kernel<1, 0><<<dim3(C / 128, 1, 3), dim3(256), 0, stream>>>(
            H1, W2, b2, H2, 256, 128, 1.f,
            (size_t)C * 256, (size_t)256 * 128, 128, (size_t)C * 128, 0);
        gemm_ln_kernel<<<dim3(C / 128, 3), dim3(256), 0, stream>>>(
            H2, W3, b3, gamma, beta, enc3, 128,
            (size_t)C * 128, (size_t)128 * 64, 64, (size_t)C * DC);
        quant_kernel<<<dim3(C / 128, 3), dim3(256), 0, stream>>>(
            enc3, cbnT, cbn, out_tok, accv + 0, off,
            (size_t)C * DC, (size_t)DC * LCB, (size_t)LCB * DC);

        // decoder: avg_q = (q0+q1+q2)/3 folded into SUM3 A-load
        gemm_kernel<1, 1><<<dim3(C / 128, 1, 1), dim3(256), 0, stream>>>(
            enc3, D1, c1, H2, 64, 128, 1.f / 3.f,
            0, 0, 0, 0, (size_t)C * DC);
        gemm_kernel<1, 0><<<dim3(C / 128, 2, 1), dim3(256), 0, stream>>>(
            H2, D2, c2, H1, 128, 256, 1.f, 0, 0, 0, 0, 0);
        gemm_dec_out_kernel<<<dim3(C / 128, 4), dim3(256), 0, stream>>>(
            H1, D3, c3, xc, rcc, accv + 1, 256, 512);
    }

    finalize_kernel<<<dim3(1), dim3(64), 0, stream>>>(
        accv, out_sc, 1.f / ((float)M * IN_DIM), 1.f / ((float)M * DC));
}